// Round 3
// baseline (490.919 us; speedup 1.0000x reference)
//
#include <hip/hip_runtime.h>
#include <cstdint>

#define IN_DIM 45
#define HDIM 128
#define DDIM 256
#define ROWS 64
#define NT 8             // row-tiles per block
#define NBLK 512         // 512 blocks * 8 tiles * 64 rows = 262144 rows

typedef unsigned short u16;
typedef __attribute__((ext_vector_type(8))) short v8s;     // 8 x bf16 fragment
typedef __attribute__((ext_vector_type(4))) float f32x4;   // MFMA accumulator
typedef __attribute__((ext_vector_type(2))) float f32x2;

__device__ __forceinline__ u16 f2bf(float x){
  uint32_t u = __float_as_uint(x);
  u += 0x7FFFu + ((u >> 16) & 1u);      // round-to-nearest-even
  return (u16)(u >> 16);
}

__device__ __forceinline__ void g2l16(const void* g, void* l){
  __builtin_amdgcn_global_load_lds(
      (const __attribute__((address_space(1))) unsigned int*)g,
      (__attribute__((address_space(3))) unsigned int*)l, 16, 0, 0);
}

// prep: weights in per-wave MFMA *fragment order* so the main kernel can load
// them straight into registers with coalesced dwordx4 loads.
// w1f (16 KB): frag f = ((wv*2+ks)*2+nt), elem (lane,j):
//    n = wv*32 + nt*16 + (lane&15); k = ks*32 + (lane>>4)*8 + j; zero-pad k>=45.
// w2f (64 KB): frag f = ((wv*4+ks)*4+ntl):
//    n = wv*64 + ntl*16 + (lane&15); k = ks*32 + (lane>>4)*8 + j.
__global__ void prep_kernel(const float* __restrict__ w1, const float* __restrict__ w2,
                            u16* __restrict__ w1f, u16* __restrict__ w2f){
  int idx = blockIdx.x*256 + threadIdx.x;
  if (idx < 8192){
    int j = idx & 7, lane = (idx >> 3) & 63, f = idx >> 9;
    int wv = f >> 2, ks = (f >> 1) & 1, nt = f & 1;
    int n = wv*32 + nt*16 + (lane & 15);
    int k = ks*32 + (lane >> 4)*8 + j;
    float v = (k < IN_DIM) ? w1[k*HDIM + n] : 0.f;
    w1f[idx] = f2bf(v);
  } else if (idx < 40960){
    int t = idx - 8192;
    int j = t & 7, lane = (t >> 3) & 63, f = t >> 9;
    int wv = f >> 4, ks = (f >> 2) & 3, ntl = f & 3;
    int n = wv*64 + ntl*16 + (lane & 15);
    int k = ks*32 + (lane >> 4)*8 + j;
    w2f[t] = f2bf(w2[k*DDIM + n]);
  }
}

// LDS map (51712 B):
//   [0,23040)       pose double buffer: 2 x (64 rows x 45 fp32 = 11520 B)
//   [23040,32256)   sx: x bf16 [64][72]  (cols 45..63 zeroed once in prologue)
//   [32256,49664)   sh: hidden bf16 [64][136]
//   [49664,51712)   stats: f32x2 [64 rows][4 waves] (sum, sumsq) partials
// Per-tile barriers: 3 (vs 10 in the per-block-staging version).
// Weights never touch LDS: each wave holds its N-slice as MFMA B-fragments
// (w1: 16 VGPR, w2: 64 VGPR), loaded once per persistent block.
__global__ __launch_bounds__(256, 2)
void posemlp_kernel(const float* __restrict__ pose,
                    const float* __restrict__ ln1g, const float* __restrict__ ln1b,
                    const float* __restrict__ b1v,  const float* __restrict__ b2v,
                    const float* __restrict__ ln2g, const float* __restrict__ ln2b,
                    const u16* __restrict__ w1f, const u16* __restrict__ w2f,
                    float* __restrict__ out)
{
  __shared__ __align__(16) unsigned char smem[51712];
  u16*   sx    = (u16*)(smem + 23040);
  u16*   sh    = (u16*)(smem + 32256);
  f32x2* stats = (f32x2*)(smem + 49664);

  const int tid  = threadIdx.x;
  const int lane = tid & 63, wv = tid >> 6;
  const int col  = lane & 15, quad = lane >> 4;

  // ---- persistent weight fragments (once per block)
  v8s b1f[2][2], b2f[4][4];
  {
    const v8s* p1 = (const v8s*)w1f;
    #pragma unroll
    for (int ks = 0; ks < 2; ++ks)
      #pragma unroll
      for (int nt = 0; nt < 2; ++nt)
        b1f[ks][nt] = p1[((wv*2 + ks)*2 + nt)*64 + lane];
    const v8s* p2 = (const v8s*)w2f;
    #pragma unroll
    for (int ks = 0; ks < 4; ++ks)
      #pragma unroll
      for (int ntl = 0; ntl < 4; ++ntl)
        b2f[ks][ntl] = p2[((wv*4 + ks)*4 + ntl)*64 + lane];
  }
  // hoisted epilogue params (wave's N-slices are loop-invariant)
  float bias1[2], bias2[4], g2[4], bt2[4];
  #pragma unroll
  for (int nt = 0; nt < 2; ++nt) bias1[nt] = b1v[wv*32 + nt*16 + col];
  #pragma unroll
  for (int ntl = 0; ntl < 4; ++ntl){
    int n = wv*64 + ntl*16 + col;
    bias2[ntl] = b2v[n]; g2[ntl] = ln2g[n]; bt2[ntl] = ln2b[n];
  }

  // zero sx once (K-pad 45..63 stays zero forever; LN1 writes only k<45)
  {
    f32x4* z = (f32x4*)sx;                 // 9216 B / 16 = 576 chunks
    for (int i = tid; i < 576; i += 256) z[i] = (f32x4){0.f,0.f,0.f,0.f};
  }
  // stage pose tile 0 into buf 0
  const size_t tile0 = (size_t)blockIdx.x * NT;
  {
    const char* psrc = (const char*)pose + tile0 * (ROWS*IN_DIM*4);
    #pragma unroll
    for (int j = 0; j < 3; ++j){
      int i = j*256 + tid;
      if (i < 720) g2l16(psrc + (size_t)i*16, smem + i*16);
    }
  }
  __syncthreads();     // drains vmcnt -> pose[0] + sx pad valid

  #pragma unroll 1
  for (int t = 0; t < NT; ++t){
    const int cur = t & 1;
    const float* posel = (const float*)(smem + cur*11520);

    // ---- LN1 (4 lanes per row) -> bf16 x
    {
      int row = tid >> 2, p = tid & 3;
      const float* pr = posel + row*IN_DIM;
      float sum = 0.f, sq = 0.f;
      for (int k = p; k < IN_DIM; k += 4){ float v = pr[k]; sum += v; sq += v*v; }
      sum += __shfl_xor(sum, 1); sum += __shfl_xor(sum, 2);
      sq  += __shfl_xor(sq, 1);  sq  += __shfl_xor(sq, 2);
      float mu = sum * (1.f/IN_DIM);
      float rs = rsqrtf(sq * (1.f/IN_DIM) - mu*mu + 1e-5f);
      u16* xr = sx + row*72;
      for (int k = p; k < IN_DIM; k += 4)
        xr[k] = f2bf((pr[k] - mu) * rs * ln1g[k] + ln1b[k]);
    }
    __syncthreads();   // sx ready; pose[cur] fully consumed

    // ---- prefetch next pose tile (drained at the h-barrier below,
    //      covered by GEMM1+GELU ~1800 cycles)
    if (t + 1 < NT){
      const char* psrc = (const char*)pose + (tile0 + t + 1) * (ROWS*IN_DIM*4);
      unsigned char* pdst = smem + (cur^1)*11520;
      #pragma unroll
      for (int j = 0; j < 3; ++j){
        int i = j*256 + tid;
        if (i < 720) g2l16(psrc + (size_t)i*16, pdst + (size_t)i*16);
      }
    }

    // ---- GEMM1 (N-split: wave wv owns H cols [32wv,32wv+32), all 64 rows)
    f32x4 acc1[4][2];
    #pragma unroll
    for (int mt = 0; mt < 4; ++mt)
      #pragma unroll
      for (int nt = 0; nt < 2; ++nt) acc1[mt][nt] = (f32x4){0.f,0.f,0.f,0.f};
    #pragma unroll
    for (int ks = 0; ks < 2; ++ks){
      v8s a[4];
      #pragma unroll
      for (int mt = 0; mt < 4; ++mt)
        a[mt] = *(const v8s*)(sx + (mt*16 + col)*72 + ks*32 + quad*8);
      #pragma unroll
      for (int mt = 0; mt < 4; ++mt)
        #pragma unroll
        for (int nt = 0; nt < 2; ++nt)
          acc1[mt][nt] = __builtin_amdgcn_mfma_f32_16x16x32_bf16(a[mt], b1f[ks][nt], acc1[mt][nt], 0, 0, 0);
    }
    // bias + exact GELU -> sh slice [all rows][32wv..32wv+32)
    #pragma unroll
    for (int mt = 0; mt < 4; ++mt)
      #pragma unroll
      for (int nt = 0; nt < 2; ++nt){
        #pragma unroll
        for (int r = 0; r < 4; ++r){
          float v = acc1[mt][nt][r] + bias1[nt];
          v = 0.5f * v * (1.f + erff(v * 0.70710678118654752f));
          sh[(mt*16 + quad*4 + r)*136 + wv*32 + nt*16 + col] = f2bf(v);
        }
      }
    __syncthreads();   // sh ready; pose[t+1] staged (vmcnt drained here)

    // ---- GEMM2 (N-split: wave wv owns out cols [64wv,64wv+64), all 64 rows)
    f32x4 acc2[4][4];
    #pragma unroll
    for (int mt = 0; mt < 4; ++mt)
      #pragma unroll
      for (int ntl = 0; ntl < 4; ++ntl) acc2[mt][ntl] = (f32x4){0.f,0.f,0.f,0.f};
    #pragma unroll
    for (int ks = 0; ks < 4; ++ks){
      v8s a[4];
      #pragma unroll
      for (int mt = 0; mt < 4; ++mt)
        a[mt] = *(const v8s*)(sh + (mt*16 + col)*136 + ks*32 + quad*8);
      #pragma unroll
      for (int mt = 0; mt < 4; ++mt)
        #pragma unroll
        for (int ntl = 0; ntl < 4; ++ntl)
          acc2[mt][ntl] = __builtin_amdgcn_mfma_f32_16x16x32_bf16(a[mt], b2f[ks][ntl], acc2[mt][ntl], 0, 0, 0);
    }

    // ---- +b2, per-wave partial LN2 stats over this wave's 64 cols
    float psum[4][4], psq[4][4];          // [mt][r]
    #pragma unroll
    for (int mt = 0; mt < 4; ++mt)
      #pragma unroll
      for (int r = 0; r < 4; ++r){ psum[mt][r] = 0.f; psq[mt][r] = 0.f; }
    #pragma unroll
    for (int mt = 0; mt < 4; ++mt)
      #pragma unroll
      for (int ntl = 0; ntl < 4; ++ntl)
        #pragma unroll
        for (int r = 0; r < 4; ++r){
          float v = acc2[mt][ntl][r] + bias2[ntl];
          acc2[mt][ntl][r] = v;
          psum[mt][r] += v; psq[mt][r] += v*v;
        }
    #pragma unroll
    for (int m = 1; m <= 8; m <<= 1){
      #pragma unroll
      for (int mt = 0; mt < 4; ++mt)
        #pragma unroll
        for (int r = 0; r < 4; ++r){
          psum[mt][r] += __shfl_xor(psum[mt][r], m);
          psq[mt][r]  += __shfl_xor(psq[mt][r],  m);
        }
    }
    if (col == 0){
      #pragma unroll
      for (int mt = 0; mt < 4; ++mt)
        #pragma unroll
        for (int r = 0; r < 4; ++r)
          stats[(mt*16 + quad*4 + r)*4 + wv] = (f32x2){psum[mt][r], psq[mt][r]};
    }
    __syncthreads();   // cross-wave stats ready

    // ---- finalize LN2 + store (wave's 64-col slice, fp32)
    const size_t rowG0 = (tile0 + t) * ROWS;
    #pragma unroll
    for (int mt = 0; mt < 4; ++mt){
      #pragma unroll
      for (int r = 0; r < 4; ++r){
        int rowL = mt*16 + quad*4 + r;
        f32x4 s0 = *(const f32x4*)&stats[rowL*4];       // (sum0,sq0,sum1,sq1)
        f32x4 s1 = *(const f32x4*)&stats[rowL*4 + 2];   // (sum2,sq2,sum3,sq3)
        float sum = s0.x + s0.z + s1.x + s1.z;
        float sq  = s0.y + s0.w + s1.y + s1.w;
        float mu = sum * (1.f/DDIM);
        float rs = rsqrtf(sq * (1.f/DDIM) - mu*mu + 1e-5f);
        float* orow = out + (rowG0 + rowL)*DDIM;
        #pragma unroll
        for (int ntl = 0; ntl < 4; ++ntl)
          orow[wv*64 + ntl*16 + col] = (acc2[mt][ntl][r] - mu) * rs * g2[ntl] + bt2[ntl];
      }
    }
    // no trailing barrier: next LN1's sx writes are fenced by this tile's
    // h-barrier (all sx readers done), pose prefetch drained there too, and
    // stats rewrite in t+1 sits behind two more barriers.
  }
}

extern "C" void kernel_launch(void* const* d_in, const int* in_sizes, int n_in,
                              void* d_out, int out_size, void* d_ws, size_t ws_size,
                              hipStream_t stream){
  const float* pose = (const float*)d_in[0];
  const float* ln1g = (const float*)d_in[1];
  const float* ln1b = (const float*)d_in[2];
  const float* w1   = (const float*)d_in[3];
  const float* b1   = (const float*)d_in[4];
  const float* w2   = (const float*)d_in[5];
  const float* b2   = (const float*)d_in[6];
  const float* ln2g = (const float*)d_in[7];
  const float* ln2b = (const float*)d_in[8];
  u16* w1f = (u16*)d_ws;
  u16* w2f = (u16*)((char*)d_ws + 16384);   // 80 KB of d_ws used
  prep_kernel<<<160, 256, 0, stream>>>(w1, w2, w1f, w2f);
  posemlp_kernel<<<NBLK, 256, 0, stream>>>(pose, ln1g, ln1b, b1, b2, ln2g, ln2b,
                                           w1f, w2f, (float*)d_out);
}

// Round 4
// 378.324 us; speedup vs baseline: 1.2976x; 1.2976x over previous
//
#include <hip/hip_runtime.h>
#include <cstdint>

#define IN_DIM 45
#define HDIM 128
#define DDIM 256
#define ROWS 64
#define NBLK 4096        // 1 row-tile (64 rows) per block

typedef unsigned short u16;
typedef __attribute__((ext_vector_type(8))) short v8s;     // 8 x bf16 fragment
typedef __attribute__((ext_vector_type(4))) float f32x4;   // MFMA accumulator
typedef __attribute__((ext_vector_type(2))) float f32x2;

__device__ __forceinline__ u16 f2bf(float x){
  uint32_t u = __float_as_uint(x);
  u += 0x7FFFu + ((u >> 16) & 1u);      // round-to-nearest-even
  return (u16)(u >> 16);
}

__device__ __forceinline__ void g2l16(const void* g, void* l){
  __builtin_amdgcn_global_load_lds(
      (const __attribute__((address_space(1))) unsigned int*)g,
      (__attribute__((address_space(3))) unsigned int*)l, 16, 0, 0);
}

// prep: weights in per-wave MFMA *fragment order* so the main kernel loads
// them straight into registers with coalesced dwordx4 loads.
// w1f (16 KB): frag f = ((wv*2+ks)*2+nt), elem (lane,j):
//    n = wv*32 + nt*16 + (lane&15); k = ks*32 + (lane>>4)*8 + j; zero-pad k>=45.
// w2f (64 KB): frag f = ((wv*4+ks)*4+ntl):
//    n = wv*64 + ntl*16 + (lane&15); k = ks*32 + (lane>>4)*8 + j.
__global__ void prep_kernel(const float* __restrict__ w1, const float* __restrict__ w2,
                            u16* __restrict__ w1f, u16* __restrict__ w2f){
  int idx = blockIdx.x*256 + threadIdx.x;
  if (idx < 8192){
    int j = idx & 7, lane = (idx >> 3) & 63, f = idx >> 9;
    int wv = f >> 2, ks = (f >> 1) & 1, nt = f & 1;
    int n = wv*32 + nt*16 + (lane & 15);
    int k = ks*32 + (lane >> 4)*8 + j;
    float v = (k < IN_DIM) ? w1[k*HDIM + n] : 0.f;
    w1f[idx] = f2bf(v);
  } else if (idx < 40960){
    int t = idx - 8192;
    int j = t & 7, lane = (t >> 3) & 63, f = t >> 9;
    int wv = f >> 4, ks = (f >> 2) & 3, ntl = f & 3;
    int n = wv*64 + ntl*16 + (lane & 15);
    int k = ks*32 + (lane >> 4)*8 + j;
    w2f[t] = f2bf(w2[k*DDIM + n]);
  }
}

// LDS map (40192 B -> 4 blocks/CU; 4 x 40192 = 160768 <= 163840):
//   [0,11520)       pose fp32 tile [64][45]
//   [11520,20736)   sx bf16 [64][72]  (k-pad 45..63 zeroed in prologue)
//   [20736,38144)   sh bf16 [64][136]; after the stats barrier reused as
//                   per-wave fp32 transpose buf [16][68] (4352 B per wave)
//   [38144,40192)   stats f32x2 [64 rows][4 waves]
// 4 barriers total. Weights never touch LDS (register fragments).
__global__ __launch_bounds__(256, 2)
void posemlp_kernel(const float* __restrict__ pose,
                    const float* __restrict__ ln1g, const float* __restrict__ ln1b,
                    const float* __restrict__ b1v,  const float* __restrict__ b2v,
                    const float* __restrict__ ln2g, const float* __restrict__ ln2b,
                    const u16* __restrict__ w1f, const u16* __restrict__ w2f,
                    float* __restrict__ out)
{
  __shared__ __align__(16) unsigned char smem[40192];
  u16*   sx    = (u16*)(smem + 11520);
  u16*   sh    = (u16*)(smem + 20736);
  f32x2* stats = (f32x2*)(smem + 38144);
  const float* posel = (const float*)smem;

  const int tid  = threadIdx.x;
  const int lane = tid & 63, wv = tid >> 6;
  const int col  = lane & 15, quad = lane >> 4;

  // ---- persistent weight fragments (loaded once, from L2)
  v8s b1f[2][2], b2f[4][4];
  {
    const v8s* p1 = (const v8s*)w1f;
    #pragma unroll
    for (int ks = 0; ks < 2; ++ks)
      #pragma unroll
      for (int nt = 0; nt < 2; ++nt)
        b1f[ks][nt] = p1[((wv*2 + ks)*2 + nt)*64 + lane];
    const v8s* p2 = (const v8s*)w2f;
    #pragma unroll
    for (int ks = 0; ks < 4; ++ks)
      #pragma unroll
      for (int ntl = 0; ntl < 4; ++ntl)
        b2f[ks][ntl] = p2[((wv*4 + ks)*4 + ntl)*64 + lane];
  }
  // hoisted epilogue params (wave's N-slices)
  float bias1[2], bias2[4], g2[4], bt2[4];
  #pragma unroll
  for (int nt = 0; nt < 2; ++nt) bias1[nt] = b1v[wv*32 + nt*16 + col];
  #pragma unroll
  for (int ntl = 0; ntl < 4; ++ntl){
    int n = wv*64 + ntl*16 + col;
    bias2[ntl] = b2v[n]; g2[ntl] = ln2g[n]; bt2[ntl] = ln2b[n];
  }

  // zero sx (k-pad stays zero; LN1 writes only k<45)
  {
    f32x4* z = (f32x4*)sx;                 // 9216 B / 16 = 576 chunks
    for (int i = tid; i < 576; i += 256) z[i] = (f32x4){0.f,0.f,0.f,0.f};
  }
  // stage pose tile (11520 B, coalesced 16 B granules)
  {
    const char* psrc = (const char*)pose + (size_t)blockIdx.x * (ROWS*IN_DIM*4);
    #pragma unroll
    for (int j = 0; j < 3; ++j){
      int i = j*256 + tid;
      if (i < 720) g2l16(psrc + (size_t)i*16, smem + i*16);
    }
  }
  __syncthreads();     // vmcnt drained: pose + sx pad valid

  // ---- LN1 (4 lanes per row) -> bf16 x
  {
    int row = tid >> 2, p = tid & 3;
    const float* pr = posel + row*IN_DIM;
    float sum = 0.f, sq = 0.f;
    for (int k = p; k < IN_DIM; k += 4){ float v = pr[k]; sum += v; sq += v*v; }
    sum += __shfl_xor(sum, 1); sum += __shfl_xor(sum, 2);
    sq  += __shfl_xor(sq, 1);  sq  += __shfl_xor(sq, 2);
    float mu = sum * (1.f/IN_DIM);
    float rs = rsqrtf(sq * (1.f/IN_DIM) - mu*mu + 1e-5f);
    u16* xr = sx + row*72;
    for (int k = p; k < IN_DIM; k += 4)
      xr[k] = f2bf((pr[k] - mu) * rs * ln1g[k] + ln1b[k]);
  }
  __syncthreads();     // sx ready

  // ---- GEMM1 (N-split: wave wv owns H cols [32wv,32wv+32), all 64 rows)
  f32x4 acc1[4][2];
  #pragma unroll
  for (int mt = 0; mt < 4; ++mt)
    #pragma unroll
    for (int nt = 0; nt < 2; ++nt) acc1[mt][nt] = (f32x4){0.f,0.f,0.f,0.f};
  #pragma unroll
  for (int ks = 0; ks < 2; ++ks){
    v8s a[4];
    #pragma unroll
    for (int mt = 0; mt < 4; ++mt)
      a[mt] = *(const v8s*)(sx + (mt*16 + col)*72 + ks*32 + quad*8);
    #pragma unroll
    for (int mt = 0; mt < 4; ++mt)
      #pragma unroll
      for (int nt = 0; nt < 2; ++nt)
        acc1[mt][nt] = __builtin_amdgcn_mfma_f32_16x16x32_bf16(a[mt], b1f[ks][nt], acc1[mt][nt], 0, 0, 0);
  }
  // bias + exact GELU -> sh slice [all rows][32wv..32wv+32)
  #pragma unroll
  for (int mt = 0; mt < 4; ++mt)
    #pragma unroll
    for (int nt = 0; nt < 2; ++nt){
      #pragma unroll
      for (int r = 0; r < 4; ++r){
        float v = acc1[mt][nt][r] + bias1[nt];
        v = 0.5f * v * (1.f + erff(v * 0.70710678118654752f));
        sh[(mt*16 + quad*4 + r)*136 + wv*32 + nt*16 + col] = f2bf(v);
      }
    }
  __syncthreads();     // sh (hidden) ready

  // ---- GEMM2 (N-split: wave wv owns out cols [64wv,64wv+64), all 64 rows)
  f32x4 acc2[4][4];
  #pragma unroll
  for (int mt = 0; mt < 4; ++mt)
    #pragma unroll
    for (int ntl = 0; ntl < 4; ++ntl) acc2[mt][ntl] = (f32x4){0.f,0.f,0.f,0.f};
  #pragma unroll
  for (int ks = 0; ks < 4; ++ks){
    v8s a[4];
    #pragma unroll
    for (int mt = 0; mt < 4; ++mt)
      a[mt] = *(const v8s*)(sh + (mt*16 + col)*136 + ks*32 + quad*8);
    #pragma unroll
    for (int mt = 0; mt < 4; ++mt)
      #pragma unroll
      for (int ntl = 0; ntl < 4; ++ntl)
        acc2[mt][ntl] = __builtin_amdgcn_mfma_f32_16x16x32_bf16(a[mt], b2f[ks][ntl], acc2[mt][ntl], 0, 0, 0);
  }

  // ---- +b2, per-wave partial LN2 stats over this wave's 64 cols
  float psum[4][4], psq[4][4];            // [mt][r]
  #pragma unroll
  for (int mt = 0; mt < 4; ++mt)
    #pragma unroll
    for (int r = 0; r < 4; ++r){ psum[mt][r] = 0.f; psq[mt][r] = 0.f; }
  #pragma unroll
  for (int mt = 0; mt < 4; ++mt)
    #pragma unroll
    for (int ntl = 0; ntl < 4; ++ntl)
      #pragma unroll
      for (int r = 0; r < 4; ++r){
        float v = acc2[mt][ntl][r] + bias2[ntl];
        acc2[mt][ntl][r] = v;
        psum[mt][r] += v; psq[mt][r] += v*v;
      }
  #pragma unroll
  for (int m = 1; m <= 8; m <<= 1){       // butterfly within 16-lane group
    #pragma unroll
    for (int mt = 0; mt < 4; ++mt)
      #pragma unroll
      for (int r = 0; r < 4; ++r){
        psum[mt][r] += __shfl_xor(psum[mt][r], m);
        psq[mt][r]  += __shfl_xor(psq[mt][r],  m);
      }
  }
  if (col == 0){
    #pragma unroll
    for (int mt = 0; mt < 4; ++mt)
      #pragma unroll
      for (int r = 0; r < 4; ++r)
        stats[(mt*16 + quad*4 + r)*4 + wv] = (f32x2){psum[mt][r], psq[mt][r]};
  }
  __syncthreads();     // cross-wave stats ready; all sh reads done -> sh reusable

  // ---- finalize LN2, transpose through per-wave LDS buf, full-line stores.
  // tb: [16 rows][68 floats] per wave (wave-private -> no barrier, only
  // wave-level lgkmcnt). Each global_store_dwordx4 has 16 lanes covering
  // 256 B contiguous per row (2 full 128 B lines) -> no write-allocate RMW.
  float* tb = (float*)(smem + 20736 + wv*4352);
  const size_t rowG0 = (size_t)blockIdx.x * ROWS;
  #pragma unroll
  for (int mt = 0; mt < 4; ++mt){
    #pragma unroll
    for (int r = 0; r < 4; ++r){
      int rowL = mt*16 + quad*4 + r;
      f32x4 s0 = *(const f32x4*)&stats[rowL*4];       // (sum0,sq0,sum1,sq1)
      f32x4 s1 = *(const f32x4*)&stats[rowL*4 + 2];   // (sum2,sq2,sum3,sq3)
      float sum = s0.x + s0.z + s1.x + s1.z;
      float sq  = s0.y + s0.w + s1.y + s1.w;
      float mu = sum * (1.f/DDIM);
      float rs = rsqrtf(sq * (1.f/DDIM) - mu*mu + 1e-5f);
      #pragma unroll
      for (int ntl = 0; ntl < 4; ++ntl)
        tb[(quad*4 + r)*68 + ntl*16 + col] =
            (acc2[mt][ntl][r] - mu) * rs * g2[ntl] + bt2[ntl];
    }
    asm volatile("s_waitcnt lgkmcnt(0)" ::: "memory");  // wave's tb writes visible
    #pragma unroll
    for (int i = 0; i < 4; ++i){
      int row16 = i*4 + quad;
      f32x4 v = *(const f32x4*)(tb + row16*68 + col*4);
      *(f32x4*)(out + (rowG0 + mt*16 + row16)*DDIM + wv*64 + col*4) = v;
    }
    // next mt's tb writes can't pass these reads: DS ops issue in order per wave
  }
}

extern "C" void kernel_launch(void* const* d_in, const int* in_sizes, int n_in,
                              void* d_out, int out_size, void* d_ws, size_t ws_size,
                              hipStream_t stream){
  const float* pose = (const float*)d_in[0];
  const float* ln1g = (const float*)d_in[1];
  const float* ln1b = (const float*)d_in[2];
  const float* w1   = (const float*)d_in[3];
  const float* b1   = (const float*)d_in[4];
  const float* w2   = (const float*)d_in[5];
  const float* b2   = (const float*)d_in[6];
  const float* ln2g = (const float*)d_in[7];
  const float* ln2b = (const float*)d_in[8];
  u16* w1f = (u16*)d_ws;
  u16* w2f = (u16*)((char*)d_ws + 16384);   // 80 KB of d_ws used
  prep_kernel<<<160, 256, 0, stream>>>(w1, w2, w1f, w2f);
  posemlp_kernel<<<NBLK, 256, 0, stream>>>(pose, ln1g, ln1b, b1, b2, ln2g, ln2b,
                                           w1f, w2f, (float*)d_out);
}